// Round 13
// baseline (284.998 us; speedup 1.0000x reference)
//
#include <hip/hip_runtime.h>
#include <math.h>

// x: [32,3,512,512] f32.
// 4 cols/lane, shuffle-free, VGPR<=64 for 8 waves/SIMD (occupancy quantum
// steps at 64/128/256 VGPR; every 8-col variant sat at 4 waves/SIMD).
// Each lane loads an 8-float window (float2+float4+float2, aligned):
// cols c0-2..c0+5. Sobel mag for 6 cols (c0-1..c0+4), 3x3 pool for 4
// (c0..c0+3) -- fully lane-local, ZERO cross-lane ops. Wave spans 256
// cols -> 2 strips per image row; strip-internal "halo" cols are real
// loads, only true image edges masked (lm: c0==0, rm: c0==508).
// State: xprev[8] + Po[8] (pair-sum ring) + Mlast[6] + CS2[6]
// (running mag-row pair-sum; replaces 3-row mag ring, same VALU, -6 reg).
// mag = raw v_sqrt_f32. Deferred /9, /81. 12 output rows/wave,
// 44 chunks (43 real + 1 dummy) x 2 strips x 96 (b,c) = 8448 waves.
// Stage 2 parallelized: 32 blocks (one per b), wave-per-channel reduce.
// Grid: (22, 96) x 256.

template <bool SAFE>
__device__ __forceinline__ void sweep12(const float* __restrict__ xb,
                                        int row0, int offL, int offM, int offR,
                                        float lm, float rm,
                                        float& s_out, float& ss_out) {
  auto load8 = [&](int r, float* o) {
    if (SAFE && (unsigned)r >= 512u) {
#pragma unroll
      for (int k = 0; k < 8; ++k) o[k] = 0.f;
      return;
    }
    const float* p = xb + (size_t)r * 512;
    float2 L = *(const float2*)(p + offL);
    float4 m = *(const float4*)(p + offM);
    float2 R = *(const float2*)(p + offR);
    o[0] = L.x * lm; o[1] = L.y * lm;
    o[2] = m.x; o[3] = m.y; o[4] = m.z; o[5] = m.w;
    o[6] = R.x * rm; o[7] = R.y * rm;
  };

  float xprev[8], Po[8], Mlast[6], CS2[6];
  float s = 0.f, ss = 0.f;

  {
    float t0[8];
    load8(row0 - 2, t0);
    load8(row0 - 1, xprev);
#pragma unroll
    for (int k = 0; k < 8; ++k) Po[k] = t0[k] + xprev[k];
  }

#pragma unroll
  for (int t = 0; t < 14; ++t) {
    float xn[8], Pn[8], mg[6];
    load8(row0 + t, xn);
#pragma unroll
    for (int k = 0; k < 8; ++k) Pn[k] = xprev[k] + xn[k];

    const int mrow = row0 + t - 1;            // mag row this step emits
    if (!SAFE || (unsigned)mrow < 512u) {     // wave-uniform; folded in FAST
      float a[8], b[8];
#pragma unroll
      for (int k = 0; k < 8; ++k) { a[k] = Po[k] + Pn[k]; b[k] = Po[k] - Pn[k]; }
#pragma unroll
      for (int k = 0; k < 6; ++k) {
        float gx = a[k] - a[k + 2];                    // horiz [1,0,-1]
        float gy = fmaf(2.f, b[k + 1], b[k] + b[k + 2]);  // horiz [1,2,1]
        float m2 = fmaf(gx, gx, 1e-6f);
        m2 = fmaf(gy, gy, m2);
        mg[k] = __builtin_amdgcn_sqrtf(m2);
      }
      mg[0] *= lm;    // image col -1 (only when c0 == 0)
      mg[5] *= rm;    // image col 512 (only when c0 == 508)
    } else {
#pragma unroll
      for (int k = 0; k < 6; ++k) mg[k] = 0.f;
    }

    if (t >= 2) {
      if (!SAFE || (unsigned)(row0 + t - 2) < 512u) {  // pool row valid
        float cs[6];
#pragma unroll
        for (int k = 0; k < 6; ++k) cs[k] = CS2[k] + mg[k];
#pragma unroll
        for (int j = 0; j < 4; ++j) {
          float tt = (cs[j] + cs[j + 2]) + cs[j + 1];
          s += tt;
          ss = fmaf(tt, tt, ss);
        }
      }
    }
    if (t >= 1) {
#pragma unroll
      for (int k = 0; k < 6; ++k) CS2[k] = Mlast[k] + mg[k];
    }
#pragma unroll
    for (int k = 0; k < 6; ++k) Mlast[k] = mg[k];
#pragma unroll
    for (int k = 0; k < 8; ++k) { xprev[k] = xn[k]; Po[k] = Pn[k]; }
  }
  s_out = s;
  ss_out = ss;
}

__global__ __launch_bounds__(256, 8) void sobel_pool_stats(
    const float* __restrict__ x, double* __restrict__ parts) {
  const int tid = threadIdx.x;
  const int lane = tid & 63;
  const int w = tid >> 6;
  const int bc = blockIdx.y;                 // 0..95
  const int wloc = blockIdx.x * 4 + w;       // 0..87
  const int strip = wloc & 1;
  const int chunk = wloc >> 1;               // 0..43 (43 = dummy)
  const int row0 = chunk * 12;

  const float* __restrict__ xb = x + (size_t)bc * (512 * 512);
  const int c0 = strip * 256 + lane * 4;
  const int offL = (c0 >= 4) ? c0 - 2 : 0;       // 8B-aligned
  const int offM = c0;                           // 16B-aligned
  const int offR = (c0 <= 504) ? c0 + 4 : 504;   // 8B-aligned
  const float lm = (c0 >= 4) ? 1.f : 0.f;
  const float rm = (c0 <= 504) ? 1.f : 0.f;

  float s, ss;
  if (chunk >= 1 && chunk <= 41)
    sweep12<false>(xb, row0, offL, offM, offR, lm, rm, s, ss);
  else
    sweep12<true>(xb, row0, offL, offM, offR, lm, rm, s, ss);

  // per-wave double reduction; fold deferred /9, /81
  double ds = (double)s * (1.0 / 9.0);
  double dss = (double)ss * (1.0 / 81.0);
  for (int off = 32; off > 0; off >>= 1) {
    ds += __shfl_down(ds, off);
    dss += __shfl_down(dss, off);
  }
  if (lane == 0) {
    size_t widx = (size_t)bc * 88 + chunk * 2 + strip;
    parts[widx * 2] = ds;
    parts[widx * 2 + 1] = dss;
  }
}

// One block per batch image b: waves 0-2 reduce channel 0-2's 88 partials,
// then feats [m0,s0,m1,s1,m2,s2] -> 6->32(relu)->64 MLP -> out[b*64..].
__global__ __launch_bounds__(256) void stats_mlp(
    const double* __restrict__ parts,
    const float* __restrict__ w1, const float* __restrict__ b1,
    const float* __restrict__ w2, const float* __restrict__ b2,
    float* __restrict__ out) {
  __shared__ float feats[6];
  __shared__ float hbuf[32];
  const int tid = threadIdx.x;
  const int lane = tid & 63;
  const int w = tid >> 6;
  const int b = blockIdx.x;                  // 0..31

  if (w < 3) {
    const int bc = b * 3 + w;
    const double2* p2 = (const double2*)(parts + (size_t)bc * 176);
    double2 v = p2[lane];
    double s = v.x, ss = v.y;
    if (lane < 24) {
      double2 u = p2[64 + lane];
      s += u.x;
      ss += u.y;
    }
    for (int off = 32; off > 0; off >>= 1) {
      s += __shfl_down(s, off);
      ss += __shfl_down(ss, off);
    }
    if (lane == 0) {
      const double N = 262144.0;
      double mean = s / N;
      double var = (ss - s * s / N) / (N - 1.0);
      if (var < 0.0) var = 0.0;
      feats[2 * w] = (float)mean;
      feats[2 * w + 1] = (float)sqrt(var);
    }
  }
  __syncthreads();

  if (tid < 32) {
    float acc = b1[tid];
#pragma unroll
    for (int k = 0; k < 6; ++k) acc += feats[k] * w1[tid * 6 + k];
    hbuf[tid] = acc > 0.f ? acc : 0.f;
  }
  __syncthreads();

  if (tid < 64) {
    float acc = b2[tid];
#pragma unroll
    for (int j = 0; j < 32; ++j) acc += hbuf[j] * w2[tid * 32 + j];
    out[(size_t)b * 64 + tid] = acc;
  }
}

extern "C" void kernel_launch(void* const* d_in, const int* in_sizes, int n_in,
                              void* d_out, int out_size, void* d_ws, size_t ws_size,
                              hipStream_t stream) {
  const float* x = (const float*)d_in[0];
  const float* w1 = (const float*)d_in[1];
  const float* b1 = (const float*)d_in[2];
  const float* w2 = (const float*)d_in[3];
  const float* b2 = (const float*)d_in[4];
  float* out = (float*)d_out;
  double* parts = (double*)d_ws;  // 96*88*2 doubles = 135168 B

  dim3 grid(22, 96);
  sobel_pool_stats<<<grid, 256, 0, stream>>>(x, parts);
  stats_mlp<<<32, 256, 0, stream>>>(parts, w1, b1, w2, b2, out);
}

// Round 14
// 35.887 us; speedup vs baseline: 7.9415x; 7.9415x over previous
//
#include <hip/hip_runtime.h>
#include <math.h>

// x: [32,3,512,512] f32.
// 4 cols/lane, shuffle-free. NO launch_bounds min-waves arg: r13's
// __launch_bounds__(256,8) made the compiler cap at VGPR=32 -> 570MB of
// scratch spill (285us). Persistent state here is ~28 floats so the
// natural allocation should land ~48-64 VGPR -> 8 waves/SIMD organically.
// Each lane loads an 8-float window (float2+float4+float2, aligned):
// cols c0-2..c0+5. Sobel mag for 6 cols (c0-1..c0+4), 3x3 pool for 4
// (c0..c0+3) -- fully lane-local, ZERO cross-lane ops. Wave spans 256
// cols -> 2 strips per image row; strip-internal halo cols are real
// loads, only true image edges masked (lm: c0==0, rm: c0==508).
// State: xprev[8] + Po[8] (pair-sum ring) + Mlast[6] + CS2[6]
// (running mag-row pair-sum). mag = raw v_sqrt_f32. Deferred /9, /81.
// 12 output rows/wave, 44 chunks (43 real + 1 dummy) x 2 strips x 96
// (b,c) = 8448 waves (~8.25/SIMD supply).
// Stage 2: 32 blocks (one per b), wave-per-channel reduce + MLP.
// Grid: (22, 96) x 256.

template <bool SAFE>
__device__ __forceinline__ void sweep12(const float* __restrict__ xb,
                                        int row0, int offL, int offM, int offR,
                                        float lm, float rm,
                                        float& s_out, float& ss_out) {
  auto load8 = [&](int r, float* o) {
    if (SAFE && (unsigned)r >= 512u) {
#pragma unroll
      for (int k = 0; k < 8; ++k) o[k] = 0.f;
      return;
    }
    const float* p = xb + (size_t)r * 512;
    float2 L = *(const float2*)(p + offL);
    float4 m = *(const float4*)(p + offM);
    float2 R = *(const float2*)(p + offR);
    o[0] = L.x * lm; o[1] = L.y * lm;
    o[2] = m.x; o[3] = m.y; o[4] = m.z; o[5] = m.w;
    o[6] = R.x * rm; o[7] = R.y * rm;
  };

  float xprev[8], Po[8], Mlast[6], CS2[6];
  float s = 0.f, ss = 0.f;

  {
    float t0[8];
    load8(row0 - 2, t0);
    load8(row0 - 1, xprev);
#pragma unroll
    for (int k = 0; k < 8; ++k) Po[k] = t0[k] + xprev[k];
  }

#pragma unroll
  for (int t = 0; t < 14; ++t) {
    float xn[8], Pn[8], mg[6];
    load8(row0 + t, xn);
#pragma unroll
    for (int k = 0; k < 8; ++k) Pn[k] = xprev[k] + xn[k];

    const int mrow = row0 + t - 1;            // mag row this step emits
    if (!SAFE || (unsigned)mrow < 512u) {     // wave-uniform; folded in FAST
      float a[8], b[8];
#pragma unroll
      for (int k = 0; k < 8; ++k) { a[k] = Po[k] + Pn[k]; b[k] = Po[k] - Pn[k]; }
#pragma unroll
      for (int k = 0; k < 6; ++k) {
        float gx = a[k] - a[k + 2];                       // horiz [1,0,-1]
        float gy = fmaf(2.f, b[k + 1], b[k] + b[k + 2]);  // horiz [1,2,1]
        float m2 = fmaf(gx, gx, 1e-6f);
        m2 = fmaf(gy, gy, m2);
        mg[k] = __builtin_amdgcn_sqrtf(m2);
      }
      mg[0] *= lm;    // image col -1 (only when c0 == 0)
      mg[5] *= rm;    // image col 512 (only when c0 == 508)
    } else {
#pragma unroll
      for (int k = 0; k < 6; ++k) mg[k] = 0.f;
    }

    if (t >= 2) {
      if (!SAFE || (unsigned)(row0 + t - 2) < 512u) {  // pool row valid
        float cs[6];
#pragma unroll
        for (int k = 0; k < 6; ++k) cs[k] = CS2[k] + mg[k];
#pragma unroll
        for (int j = 0; j < 4; ++j) {
          float tt = (cs[j] + cs[j + 2]) + cs[j + 1];
          s += tt;
          ss = fmaf(tt, tt, ss);
        }
      }
    }
    if (t >= 1) {
#pragma unroll
      for (int k = 0; k < 6; ++k) CS2[k] = Mlast[k] + mg[k];
    }
#pragma unroll
    for (int k = 0; k < 6; ++k) Mlast[k] = mg[k];
#pragma unroll
    for (int k = 0; k < 8; ++k) { xprev[k] = xn[k]; Po[k] = Pn[k]; }
  }
  s_out = s;
  ss_out = ss;
}

__global__ __launch_bounds__(256) void sobel_pool_stats(
    const float* __restrict__ x, double* __restrict__ parts) {
  const int tid = threadIdx.x;
  const int lane = tid & 63;
  const int w = tid >> 6;
  const int bc = blockIdx.y;                 // 0..95
  const int wloc = blockIdx.x * 4 + w;       // 0..87
  const int strip = wloc & 1;
  const int chunk = wloc >> 1;               // 0..43 (43 = dummy)
  const int row0 = chunk * 12;

  const float* __restrict__ xb = x + (size_t)bc * (512 * 512);
  const int c0 = strip * 256 + lane * 4;
  const int offL = (c0 >= 4) ? c0 - 2 : 0;       // 8B-aligned
  const int offM = c0;                           // 16B-aligned
  const int offR = (c0 <= 504) ? c0 + 4 : 504;   // 8B-aligned
  const float lm = (c0 >= 4) ? 1.f : 0.f;
  const float rm = (c0 <= 504) ? 1.f : 0.f;

  float s, ss;
  if (chunk >= 1 && chunk <= 41)
    sweep12<false>(xb, row0, offL, offM, offR, lm, rm, s, ss);
  else
    sweep12<true>(xb, row0, offL, offM, offR, lm, rm, s, ss);

  // per-wave double reduction; fold deferred /9, /81
  double ds = (double)s * (1.0 / 9.0);
  double dss = (double)ss * (1.0 / 81.0);
  for (int off = 32; off > 0; off >>= 1) {
    ds += __shfl_down(ds, off);
    dss += __shfl_down(dss, off);
  }
  if (lane == 0) {
    size_t widx = (size_t)bc * 88 + chunk * 2 + strip;
    parts[widx * 2] = ds;
    parts[widx * 2 + 1] = dss;
  }
}

// One block per batch image b: waves 0-2 reduce channel 0-2's 88 partials,
// then feats [m0,s0,m1,s1,m2,s2] -> 6->32(relu)->64 MLP -> out[b*64..].
__global__ __launch_bounds__(256) void stats_mlp(
    const double* __restrict__ parts,
    const float* __restrict__ w1, const float* __restrict__ b1,
    const float* __restrict__ w2, const float* __restrict__ b2,
    float* __restrict__ out) {
  __shared__ float feats[6];
  __shared__ float hbuf[32];
  const int tid = threadIdx.x;
  const int lane = tid & 63;
  const int w = tid >> 6;
  const int b = blockIdx.x;                  // 0..31

  if (w < 3) {
    const int bc = b * 3 + w;
    const double2* p2 = (const double2*)(parts + (size_t)bc * 176);
    double2 v = p2[lane];
    double s = v.x, ss = v.y;
    if (lane < 24) {
      double2 u = p2[64 + lane];
      s += u.x;
      ss += u.y;
    }
    for (int off = 32; off > 0; off >>= 1) {
      s += __shfl_down(s, off);
      ss += __shfl_down(ss, off);
    }
    if (lane == 0) {
      const double N = 262144.0;
      double mean = s / N;
      double var = (ss - s * s / N) / (N - 1.0);
      if (var < 0.0) var = 0.0;
      feats[2 * w] = (float)mean;
      feats[2 * w + 1] = (float)sqrt(var);
    }
  }
  __syncthreads();

  if (tid < 32) {
    float acc = b1[tid];
#pragma unroll
    for (int k = 0; k < 6; ++k) acc += feats[k] * w1[tid * 6 + k];
    hbuf[tid] = acc > 0.f ? acc : 0.f;
  }
  __syncthreads();

  if (tid < 64) {
    float acc = b2[tid];
#pragma unroll
    for (int j = 0; j < 32; ++j) acc += hbuf[j] * w2[tid * 32 + j];
    out[(size_t)b * 64 + tid] = acc;
  }
}

extern "C" void kernel_launch(void* const* d_in, const int* in_sizes, int n_in,
                              void* d_out, int out_size, void* d_ws, size_t ws_size,
                              hipStream_t stream) {
  const float* x = (const float*)d_in[0];
  const float* w1 = (const float*)d_in[1];
  const float* b1 = (const float*)d_in[2];
  const float* w2 = (const float*)d_in[3];
  const float* b2 = (const float*)d_in[4];
  float* out = (float*)d_out;
  double* parts = (double*)d_ws;  // 96*88*2 doubles = 135168 B

  dim3 grid(22, 96);
  sobel_pool_stats<<<grid, 256, 0, stream>>>(x, parts);
  stats_mlp<<<32, 256, 0, stream>>>(parts, w1, b1, w2, b2, out);
}

// Round 15
// 30.200 us; speedup vs baseline: 9.4371x; 1.1883x over previous
//
#include <hip/hip_runtime.h>
#include <math.h>

// x: [32,3,512,512] f32.
// Stage 1 = r9 verbatim (best measured: ~26.5us): register-only row sweep,
// 8 cols/lane (2 aligned float4 loads/row; wave spans 512 cols), Sobel via
// rolling vertical pair-sums, 4 shuffles/mag row + 2/pool row, builtin
// v_sqrt_f32, 12 output rows/wave, 44 chunks/(b,c) (43 real + 1 dummy),
// 4224 waves. Structural alternatives (8-row chunks, prefetch rings,
// LDS staging, 4-col shuffle-free) all regressed across r10-r14.
// Stage 2 = r14's parallel form (proven correct): 32 blocks, one per batch
// image; waves 0-2 reduce each channel's 44 double2 partials lane-parallel.
// Grid: (11, 96) x 256  +  (32) x 256.

__global__ __launch_bounds__(256) void sobel_pool_stats(
    const float* __restrict__ x, double* __restrict__ parts) {
  const int tid = threadIdx.x;
  const int lane = tid & 63;
  const int w = tid >> 6;
  const int bc = blockIdx.y;                 // 0..95
  const int chunk = blockIdx.x * 4 + w;      // 0..43 (43 = dummy)
  const int row0 = chunk * 12;

  const float* __restrict__ xb = x + (size_t)bc * (512 * 512) + lane * 8;

  auto load8 = [&](int r, float* o) {
    if ((unsigned)r < 512u) {                // wave-uniform branch
      const float* p = xb + (size_t)r * 512;
      float4 u = *(const float4*)(p);
      float4 v = *(const float4*)(p + 4);
      o[0] = u.x; o[1] = u.y; o[2] = u.z; o[3] = u.w;
      o[4] = v.x; o[5] = v.y; o[6] = v.z; o[7] = v.w;
    } else {
#pragma unroll
      for (int k = 0; k < 8; ++k) o[k] = 0.f;
    }
  };

  float S[8], X[8];
  {
    float t0[8], t1[8];
    load8(row0 - 2, t0);
    load8(row0 - 1, t1);
#pragma unroll
    for (int k = 0; k < 8; ++k) { S[k] = t0[k] + t1[k]; X[k] = t1[k]; }
  }

  // Emit mag row rm (consumes x[rm+1]); advances S,X. mg=0 if rm OOB.
  auto magstep = [&](int rm, float* mg) {
    float xn[8], S2[8], a[8], b[8];
    load8(rm + 1, xn);
#pragma unroll
    for (int k = 0; k < 8; ++k) S2[k] = X[k] + xn[k];
#pragma unroll
    for (int k = 0; k < 8; ++k) { a[k] = S[k] + S2[k]; b[k] = S[k] - S2[k]; }
    float aL = __shfl_up(a[7], 1), aR = __shfl_down(a[0], 1);
    float bL = __shfl_up(b[7], 1), bR = __shfl_down(b[0], 1);
    if (lane == 0)  { aL = 0.f; bL = 0.f; }   // image col -1 = 0
    if (lane == 63) { aR = 0.f; bR = 0.f; }   // image col 512 = 0
    const float rmask = ((unsigned)rm < 512u) ? 1.f : 0.f;
#pragma unroll
    for (int j = 0; j < 8; ++j) {
      float am = j ? a[j - 1] : aL;
      float ap = (j < 7) ? a[j + 1] : aR;
      float bm = j ? b[j - 1] : bL;
      float bp = (j < 7) ? b[j + 1] : bR;
      float gx = am - ap;                      // horiz [1,0,-1]
      float gy = fmaf(2.f, b[j], bm + bp);     // horiz [1,2,1]
      float m2 = fmaf(gx, gx, 1e-6f);
      m2 = fmaf(gy, gy, m2);
      mg[j] = __builtin_amdgcn_sqrtf(m2) * rmask;
    }
#pragma unroll
    for (int k = 0; k < 8; ++k) { S[k] = S2[k]; X[k] = xn[k]; }
  };

  float MM[8], MC[8], MP[8];
  magstep(row0 - 1, MM);
  magstep(row0, MC);

  float s = 0.f, ss = 0.f;
#pragma unroll
  for (int i = 0; i < 12; ++i) {
    magstep(row0 + 1 + i, MP);               // mag[r+1]
    if ((unsigned)(row0 + i) < 512u) {       // wave-uniform: real output row
      float cs[8];
#pragma unroll
      for (int k = 0; k < 8; ++k) cs[k] = (MM[k] + MP[k]) + MC[k];
      float csL = __shfl_up(cs[7], 1), csR = __shfl_down(cs[0], 1);
      if (lane == 0) csL = 0.f;
      if (lane == 63) csR = 0.f;
#pragma unroll
      for (int j = 0; j < 8; ++j) {
        float cm = j ? cs[j - 1] : csL;
        float cp = (j < 7) ? cs[j + 1] : csR;
        float t = (cm + cp) + cs[j];
        s += t;
        ss = fmaf(t, t, ss);
      }
    }
#pragma unroll
    for (int k = 0; k < 8; ++k) { MM[k] = MC[k]; MC[k] = MP[k]; }
  }

  // per-wave double reduction; fold deferred /9, /81
  double ds = (double)s * (1.0 / 9.0);
  double dss = (double)ss * (1.0 / 81.0);
  for (int off = 32; off > 0; off >>= 1) {
    ds += __shfl_down(ds, off);
    dss += __shfl_down(dss, off);
  }
  if (lane == 0) {
    size_t idx = ((size_t)bc * 44 + chunk) * 2;
    parts[idx] = ds;
    parts[idx + 1] = dss;
  }
}

// One block per batch image b: waves 0-2 reduce channel 0-2's 44 double2
// partials lane-parallel, then feats [m0,s0,m1,s1,m2,s2] -> MLP -> out.
__global__ __launch_bounds__(256) void stats_mlp(
    const double* __restrict__ parts,
    const float* __restrict__ w1, const float* __restrict__ b1,
    const float* __restrict__ w2, const float* __restrict__ b2,
    float* __restrict__ out) {
  __shared__ float feats[6];
  __shared__ float hbuf[32];
  const int tid = threadIdx.x;
  const int lane = tid & 63;
  const int w = tid >> 6;
  const int b = blockIdx.x;                  // 0..31

  if (w < 3) {
    const int bc = b * 3 + w;
    const double2* p2 = (const double2*)(parts + (size_t)bc * 88);
    double s = 0.0, ss = 0.0;
    if (lane < 44) {
      double2 v = p2[lane];
      s = v.x;
      ss = v.y;
    }
    for (int off = 32; off > 0; off >>= 1) {
      s += __shfl_down(s, off);
      ss += __shfl_down(ss, off);
    }
    if (lane == 0) {
      const double N = 262144.0;
      double mean = s / N;
      double var = (ss - s * s / N) / (N - 1.0);
      if (var < 0.0) var = 0.0;
      feats[2 * w] = (float)mean;
      feats[2 * w + 1] = (float)sqrt(var);
    }
  }
  __syncthreads();

  if (tid < 32) {
    float acc = b1[tid];
#pragma unroll
    for (int k = 0; k < 6; ++k) acc += feats[k] * w1[tid * 6 + k];
    hbuf[tid] = acc > 0.f ? acc : 0.f;
  }
  __syncthreads();

  if (tid < 64) {
    float acc = b2[tid];
#pragma unroll
    for (int j = 0; j < 32; ++j) acc += hbuf[j] * w2[tid * 32 + j];
    out[(size_t)b * 64 + tid] = acc;
  }
}

extern "C" void kernel_launch(void* const* d_in, const int* in_sizes, int n_in,
                              void* d_out, int out_size, void* d_ws, size_t ws_size,
                              hipStream_t stream) {
  const float* x = (const float*)d_in[0];
  const float* w1 = (const float*)d_in[1];
  const float* b1 = (const float*)d_in[2];
  const float* w2 = (const float*)d_in[3];
  const float* b2 = (const float*)d_in[4];
  float* out = (float*)d_out;
  double* parts = (double*)d_ws;  // 96*44*2 doubles = 67584 B

  dim3 grid(11, 96);
  sobel_pool_stats<<<grid, 256, 0, stream>>>(x, parts);
  stats_mlp<<<32, 256, 0, stream>>>(parts, w1, b1, w2, b2, out);
}